// Round 1
// baseline (179.226 us; speedup 1.0000x reference)
//
#include <hip/hip_runtime.h>
#include <hip/hip_bf16.h>

// SparseLoRAMoE: out[t,d] = 2 * sum_k routing[t,k] *
//                 sum_r silu(dot(x[t,:], w_a[e_k,r,:])) * w_b[e_k,d,r]
// B=2,S=2048 -> 4096 tokens; D_IN=D_OUT=2048; E=16; R=16; K=2. fp32 everywhere.
//
// Round 0 structure: one block (256 thr) per token.
//  - x row staged in LDS (8 KB), float4 coalesced.
//  - Stage A: 32 dots (2 experts x 16 ranks), each of 4 waves owns 8 pairs,
//    lane-strided float4 MACs + 64-lane shuffle reduce, silu -> LDS.
//  - Stage B: thread t computes out columns d = t, t+256, ...; w_b[e,d,0:16]
//    is 16 contiguous floats per thread -> wave reads 4 KB contiguous.

#define NDIM 2048
#define RANK 16
#define TOPK 2

__global__ __launch_bounds__(256) void sparse_lora_moe_kernel(
    const float* __restrict__ x,        // [T, 2048]
    const float* __restrict__ routing,  // [T, 2]
    const int*   __restrict__ idxs,     // [T, 2]
    const float* __restrict__ wa,       // [16, 16, 2048]
    const float* __restrict__ wb,       // [16, 2048, 16]
    float* __restrict__ out)            // [T, 2048]
{
    const int t   = blockIdx.x;   // token index
    const int tid = threadIdx.x;

    __shared__ float xs[NDIM];          // 8 KB
    __shared__ float as[TOPK * RANK];   // 32 silu'd activations

    // ---- stage x row into LDS (float4, coalesced) ----
    const float4* xg  = (const float4*)(x + (size_t)t * NDIM);
    float4*       xs4 = (float4*)xs;
    for (int i = tid; i < NDIM / 4; i += 256) xs4[i] = xg[i];

    const int   e0 = idxs[t * TOPK + 0];
    const int   e1 = idxs[t * TOPK + 1];
    const float r0 = routing[t * TOPK + 0];
    const float r1 = routing[t * TOPK + 1];

    __syncthreads();

    // ---- Stage A: 32 dot products of length 2048 ----
    const int wave = tid >> 6;
    const int lane = tid & 63;
    for (int p = wave; p < TOPK * RANK; p += 4) {
        const int k = p >> 4;         // 0 or 1
        const int r = p & 15;
        const int e = k ? e1 : e0;
        const float4* wrow = (const float4*)(wa + ((size_t)e * RANK + r) * NDIM);
        float acc = 0.f;
        for (int i = lane; i < NDIM / 4; i += 64) {
            const float4 wv = wrow[i];
            const float4 xv = xs4[i];
            acc += wv.x * xv.x + wv.y * xv.y + wv.z * xv.z + wv.w * xv.w;
        }
        // 64-lane butterfly reduce
        #pragma unroll
        for (int off = 32; off > 0; off >>= 1) acc += __shfl_down(acc, off);
        if (lane == 0) {
            as[p] = acc / (1.f + __expf(-acc));   // silu
        }
    }
    __syncthreads();

    // ---- Stage B: out[d] for d = tid, tid+256, ... ----
    const float* wb0base = wb + (size_t)e0 * NDIM * RANK;
    const float* wb1base = wb + (size_t)e1 * NDIM * RANK;
    for (int d = tid; d < NDIM; d += 256) {
        const float4* w0 = (const float4*)(wb0base + (size_t)d * RANK);
        const float4* w1 = (const float4*)(wb1base + (size_t)d * RANK);
        float s0 = 0.f, s1 = 0.f;
        #pragma unroll
        for (int q = 0; q < RANK / 4; q++) {
            const float4 a = w0[q];
            const float4 b = w1[q];
            s0 += a.x * as[q * 4 + 0] + a.y * as[q * 4 + 1]
                + a.z * as[q * 4 + 2] + a.w * as[q * 4 + 3];
            s1 += b.x * as[RANK + q * 4 + 0] + b.y * as[RANK + q * 4 + 1]
                + b.z * as[RANK + q * 4 + 2] + b.w * as[RANK + q * 4 + 3];
        }
        out[(size_t)t * NDIM + d] = 2.0f * (r0 * s0 + r1 * s1);
    }
}

extern "C" void kernel_launch(void* const* d_in, const int* in_sizes, int n_in,
                              void* d_out, int out_size, void* d_ws, size_t ws_size,
                              hipStream_t stream) {
    const float* x       = (const float*)d_in[0];
    const float* routing = (const float*)d_in[1];
    const int*   idxs    = (const int*)  d_in[2];
    const float* wa      = (const float*)d_in[3];
    const float* wb      = (const float*)d_in[4];
    float*       out     = (float*)d_out;

    const int tokens = 2 * 2048;  // B * S
    sparse_lora_moe_kernel<<<tokens, 256, 0, stream>>>(x, routing, idxs, wa, wb, out);
}